// Round 6
// baseline (379.799 us; speedup 1.0000x reference)
//
#include <hip/hip_runtime.h>

typedef __attribute__((ext_vector_type(8))) short short8;
typedef __attribute__((ext_vector_type(4))) float f32x4;

#define T_ 1024
#define D_ 64
#define CSC 0.18033688f   // 0.125 * log2(e)

static __device__ __forceinline__ unsigned short f2bf(float f) {
    union { float f; unsigned u; } x; x.f = f;
    unsigned r = x.u + 0x7fffu + ((x.u >> 16) & 1u);
    return (unsigned short)(r >> 16);
}
static __device__ __forceinline__ float fexp2(float x) {
    return __builtin_amdgcn_exp2f(fminf(x, 60.f));
}

// ---- prefetch staging helpers: 16 floats/thread (row tid>>2, cols (tid&3)*16 ..+15)
static __device__ __forceinline__ void loadT(f32x4 (&t)[4], const float* __restrict__ src, int tid) {
    const int r = tid >> 2, d0 = (tid & 3) * 16;
    const float* s = src + r * 64 + d0;
    t[0] = *(const f32x4*)(s + 0);
    t[1] = *(const f32x4*)(s + 4);
    t[2] = *(const f32x4*)(s + 8);
    t[3] = *(const f32x4*)(s + 12);
}
// row-major bf16 store, XOR-swizzled (same layout as validated stage64x64)
static __device__ __forceinline__ void writeK(unsigned short* dst, const f32x4 (&t)[4], int tid) {
    const int r = tid >> 2, d0 = (tid & 3) * 16;
    #pragma unroll
    for (int h = 0; h < 2; ++h) {
        short8 pk;
        #pragma unroll
        for (int i = 0; i < 8; ++i) {
            const int e = h * 8 + i;
            pk[i] = (short)f2bf(t[e >> 2][e & 3]);
        }
        *(short8*)&dst[((r * 64 + d0 + h * 8) ^ ((r & 7) << 3))] = pk;
    }
}
// transposed bf16 store (dst[d][s]=src[s][d]), same swizzle as validated stage64x64T
static __device__ __forceinline__ void writeVT(unsigned short* dst, const f32x4 (&t)[4], int tid) {
    const int r = tid >> 2, d0 = (tid & 3) * 16;
    #pragma unroll
    for (int i = 0; i < 16; ++i) {
        const int dd = d0 + i;
        dst[((dd * 64 + r) ^ ((dd & 7) << 3))] = f2bf(t[i >> 2][i & 3]);
    }
}
// Q staging (prologue only)
static __device__ __forceinline__ void stageQ(const float* __restrict__ src,
                                              unsigned short* dst, int tid) {
    f32x4 t[4];
    loadT(t, src, tid);
    writeK(dst, t, tid);
}

__global__ __launch_bounds__(256, 4) void relattn(
    const float* __restrict__ qg, const float* __restrict__ kg,
    const float* __restrict__ vg, const float* __restrict__ embk,
    const float* __restrict__ embv,
    float* __restrict__ outg, float* __restrict__ attng)
{
    // exact 40960 B = 160 KiB / 4 blocks
    __shared__ __align__(16) unsigned char lds[40960];
    unsigned short* QPt  = (unsigned short*)(lds);          //  8192 B: Q -> P
    unsigned short* Kt   = (unsigned short*)(lds + 8192);   //  8192 B
    unsigned short* Vt   = (unsigned short*)(lds + 16384);  //  8192 B: V^T
    float*          biasS = (float*)(lds + 24576);          //  8448 B: [64][33]
    float*          wS    = (float*)(lds + 33024);          //  7936 B: [64][31] interior
    float*          embvS = (float*)(lds);                  //  epilogue alias (QPt/Kt dead)

    const int tid  = threadIdx.x;
    const int lane = tid & 63;
    const int wv   = tid >> 6;
    const int g16  = lane >> 4;
    const int l16  = lane & 15;
    const int rbase = wv * 16 + g16 * 4;

    // XCD swizzle: all 16 t-tiles of a bh group on one XCD (L2-resident K/V)
    const int lg = ((blockIdx.x & 7) << 7) | (blockIdx.x >> 3);
    const int bh = lg >> 4;
    const int t0 = (lg & 15) * 64;
    const int dtile = t0 >> 6;
    const long base = (long)bh * (T_ * D_);

    // ---------- prologue ----------
    stageQ(qg + base + (long)t0 * D_, QPt, tid);
    for (int i = tid; i < 64 * 31; i += 256) wS[i] = 0.f;
    __syncthreads();

    // bias[r][j] = CSC * (q_fp32[t0+r] . emb_k[j])
    for (int p = tid; p < 64 * 33; p += 256) {
        const int r = p / 33, j = p - r * 33;
        const float* qr = qg + base + (long)(t0 + r) * D_;
        const float* er = embk + j * D_;
        float acc = 0.f;
        #pragma unroll
        for (int d = 0; d < 64; d += 4) {
            f32x4 a = *(const f32x4*)(qr + d);
            f32x4 b = *(const f32x4*)(er + d);
            acc += a[0] * b[0] + a[1] * b[1] + a[2] * b[2] + a[3] * b[3];
        }
        biasS[r * 33 + j] = acc * CSC;
    }

    // hoist Q A-frags (rows 16*wv + l16)
    short8 qfrag[2];
    {
        const int r = wv * 16 + l16;
        const int sw = (r & 7) << 3;
        qfrag[0] = *(short8*)&QPt[((r * 64 + 0  + g16 * 8) ^ sw)];
        qfrag[1] = *(short8*)&QPt[((r * 64 + 32 + g16 * 8) ^ sw)];
    }

    // prefetch K tile 0
    f32x4 kreg[4];
    loadT(kreg, kg + base, tid);
    __syncthreads();   // biasS visible

    float bias_m[4], bias_p[4];
    #pragma unroll
    for (int j = 0; j < 4; ++j) {
        bias_m[j] = biasS[(rbase + j) * 33 + 0];
        bias_p[j] = biasS[(rbase + j) * 33 + 32];
    }

    // ---------- sweep 1: Z only, prefetched ----------
    float zacc[4] = {0.f, 0.f, 0.f, 0.f};
    for (int tile = 0; tile < 16; ++tile) {
        __syncthreads();                 // Kt free (prev readers done)
        writeK(Kt, kreg, tid);
        if (tile < 15) loadT(kreg, kg + base + (long)(tile + 1) * 64 * D_, tid);
        __syncthreads();                 // Kt ready; prefetch in flight under compute

        f32x4 acc[4];
        #pragma unroll
        for (int sc = 0; sc < 4; ++sc) {
            f32x4 a = {0.f, 0.f, 0.f, 0.f};
            #pragma unroll
            for (int ks = 0; ks < 2; ++ks) {
                const int r = sc * 16 + l16;
                short8 bf = *(short8*)&Kt[((r * 64 + ks * 32 + g16 * 8) ^ ((r & 7) << 3))];
                a = __builtin_amdgcn_mfma_f32_16x16x32_bf16(qfrag[ks], bf, a, 0, 0, 0);
            }
            acc[sc] = a;
        }
        if (tile < dtile - 1) {
            #pragma unroll
            for (int j = 0; j < 4; ++j)
                #pragma unroll
                for (int sc = 0; sc < 4; ++sc)
                    zacc[j] += fexp2(fmaf(acc[sc][j], CSC, bias_m[j]));
        } else if (tile > dtile + 1) {
            #pragma unroll
            for (int j = 0; j < 4; ++j)
                #pragma unroll
                for (int sc = 0; sc < 4; ++sc)
                    zacc[j] += fexp2(fmaf(acc[sc][j], CSC, bias_p[j]));
        } else {
            #pragma unroll
            for (int j = 0; j < 4; ++j) {
                const int rl = rbase + j;
                const int tg = t0 + rl;
                #pragma unroll
                for (int sc = 0; sc < 4; ++sc) {
                    const int sg = tile * 64 + sc * 16 + l16;
                    int dsr = sg - tg;
                    int dc = dsr < -16 ? -16 : (dsr > 16 ? 16 : dsr);
                    const float b = biasS[rl * 33 + dc + 16];
                    zacc[j] += fexp2(fmaf(acc[sc][j], CSC, b));
                }
            }
        }
    }
    float iZ[4];
    #pragma unroll
    for (int j = 0; j < 4; ++j) {
        float z = zacc[j];
        #pragma unroll
        for (int o = 1; o < 16; o <<= 1) z += __shfl_xor(z, o);
        iZ[j] = 1.f / z;
    }

    // ---------- sweep 2: attn write + PV, K/V prefetched ----------
    f32x4 oacc[4];
    {
        f32x4 z = {0.f, 0.f, 0.f, 0.f};
        #pragma unroll
        for (int dc = 0; dc < 4; ++dc) oacc[dc] = z;
    }
    float ps0[4]  = {0.f, 0.f, 0.f, 0.f};
    float ps32[4] = {0.f, 0.f, 0.f, 0.f};
    float* attnB = attng + (long)bh * T_ * T_;

    f32x4 vreg[4];
    loadT(kreg, kg + base, tid);
    loadT(vreg, vg + base, tid);

    for (int tile = 0; tile < 16; ++tile) {
        __syncthreads();                 // Kt/Vt free (prev readers done)
        writeK (Kt, kreg, tid);
        writeVT(Vt, vreg, tid);
        if (tile < 15) {
            loadT(kreg, kg + base + (long)(tile + 1) * 64 * D_, tid);
            loadT(vreg, vg + base + (long)(tile + 1) * 64 * D_, tid);
        }
        __syncthreads();                 // tiles ready; prefetch in flight

        f32x4 acc[4];
        #pragma unroll
        for (int sc = 0; sc < 4; ++sc) {
            f32x4 a = {0.f, 0.f, 0.f, 0.f};
            #pragma unroll
            for (int ks = 0; ks < 2; ++ks) {
                const int r = sc * 16 + l16;
                short8 bf = *(short8*)&Kt[((r * 64 + ks * 32 + g16 * 8) ^ ((r & 7) << 3))];
                a = __builtin_amdgcn_mfma_f32_16x16x32_bf16(qfrag[ks], bf, a, 0, 0, 0);
            }
            acc[sc] = a;
        }

        if (tile < dtile - 1) {
            #pragma unroll
            for (int j = 0; j < 4; ++j) {
                const int rl = rbase + j;
                const int tg = t0 + rl;
                #pragma unroll
                for (int sc = 0; sc < 4; ++sc) {
                    const int sl = sc * 16 + l16;
                    const float a = fexp2(fmaf(acc[sc][j], CSC, bias_m[j])) * iZ[j];
                    attnB[(long)tg * T_ + tile * 64 + sl] = a;
                    QPt[((rl * 64 + sl) ^ ((rl & 7) << 3))] = f2bf(a);
                    ps0[j] += a;
                }
            }
        } else if (tile > dtile + 1) {
            #pragma unroll
            for (int j = 0; j < 4; ++j) {
                const int rl = rbase + j;
                const int tg = t0 + rl;
                #pragma unroll
                for (int sc = 0; sc < 4; ++sc) {
                    const int sl = sc * 16 + l16;
                    const float a = fexp2(fmaf(acc[sc][j], CSC, bias_p[j])) * iZ[j];
                    attnB[(long)tg * T_ + tile * 64 + sl] = a;
                    QPt[((rl * 64 + sl) ^ ((rl & 7) << 3))] = f2bf(a);
                    ps32[j] += a;
                }
            }
        } else {
            #pragma unroll
            for (int j = 0; j < 4; ++j) {
                const int rl = rbase + j;
                const int tg = t0 + rl;
                #pragma unroll
                for (int sc = 0; sc < 4; ++sc) {
                    const int sl = sc * 16 + l16;
                    const int sg = tile * 64 + sl;
                    const int dsr = sg - tg;
                    int dc = dsr < -16 ? -16 : (dsr > 16 ? 16 : dsr);
                    const float b = biasS[rl * 33 + dc + 16];
                    const float a = fexp2(fmaf(acc[sc][j], CSC, b)) * iZ[j];
                    attnB[(long)tg * T_ + sg] = a;
                    QPt[((rl * 64 + sl) ^ ((rl & 7) << 3))] = f2bf(a);
                    if (dsr <= -16)      ps0[j]  += a;
                    else if (dsr >= 16)  ps32[j] += a;
                    else                 wS[rl * 31 + dsr + 15] = a;
                }
            }
        }

        // PV: A = P (own wave rows), B = V^T
        #pragma unroll
        for (int ks = 0; ks < 2; ++ks) {
            const int rp = wv * 16 + l16;
            short8 pa = *(short8*)&QPt[((rp * 64 + ks * 32 + g16 * 8) ^ ((rp & 7) << 3))];
            #pragma unroll
            for (int dc = 0; dc < 4; ++dc) {
                const int rv = dc * 16 + l16;
                short8 vb = *(short8*)&Vt[((rv * 64 + ks * 32 + g16 * 8) ^ ((rv & 7) << 3))];
                oacc[dc] = __builtin_amdgcn_mfma_f32_16x16x32_bf16(pa, vb, oacc[dc], 0, 0, 0);
            }
        }
    }

    // ---------- epilogue staging: emb_v into dead QPt/Kt region ----------
    __syncthreads();   // all PV reads of QPt done
    for (int i = tid; i < 33 * 64; i += 256) embvS[i] = embv[i];

    // boundary-bucket reduction (register-only, overlaps staging)
    float w0r[4], w32r[4];
    #pragma unroll
    for (int j = 0; j < 4; ++j) {
        float a0 = ps0[j], a2 = ps32[j];
        #pragma unroll
        for (int o = 1; o < 16; o <<= 1) {
            a0 += __shfl_xor(a0, o);
            a2 += __shfl_xor(a2, o);
        }
        w0r[j] = a0; w32r[j] = a2;
    }
    __syncthreads();   // embvS + wS visible

    // ---------- epilogue: out = PV + sum_j w[t][j]*emb_v[j] ----------
    float vals[4][4];
    #pragma unroll
    for (int j = 0; j < 4; ++j)
        #pragma unroll
        for (int dc = 0; dc < 4; ++dc)
            vals[j][dc] = oacc[dc][j]
                        + w0r[j]  * embvS[0 * 64  + dc * 16 + l16]
                        + w32r[j] * embvS[32 * 64 + dc * 16 + l16];
    for (int jj = 1; jj < 32; ++jj) {
        float e[4];
        #pragma unroll
        for (int dc = 0; dc < 4; ++dc) e[dc] = embvS[jj * 64 + dc * 16 + l16];
        #pragma unroll
        for (int j = 0; j < 4; ++j) {
            const float w = wS[(rbase + j) * 31 + jj - 1];
            #pragma unroll
            for (int dc = 0; dc < 4; ++dc) vals[j][dc] += w * e[dc];
        }
    }
    #pragma unroll
    for (int j = 0; j < 4; ++j) {
        const int tg = t0 + rbase + j;
        #pragma unroll
        for (int dc = 0; dc < 4; ++dc)
            outg[base + (long)tg * D_ + dc * 16 + l16] = vals[j][dc];
    }
}

extern "C" void kernel_launch(void* const* d_in, const int* in_sizes, int n_in,
                              void* d_out, int out_size, void* d_ws, size_t ws_size,
                              hipStream_t stream) {
    const float* q    = (const float*)d_in[0];
    const float* k    = (const float*)d_in[1];
    const float* v    = (const float*)d_in[2];
    const float* embk = (const float*)d_in[3];
    const float* embv = (const float*)d_in[4];
    float* out  = (float*)d_out;
    float* attn = out + (long)4 * 16 * 1024 * 64;
    relattn<<<dim3(4 * 16 * 16), dim3(256), 0, stream>>>(q, k, v, embk, embv, out, attn);
}

// Round 7
// 249.741 us; speedup vs baseline: 1.5208x; 1.5208x over previous
//
#include <hip/hip_runtime.h>

typedef __attribute__((ext_vector_type(8))) short short8;
typedef __attribute__((ext_vector_type(4))) float f32x4;
typedef __attribute__((ext_vector_type(4))) unsigned short u16x4;

#define T_ 1024
#define D_ 64
#define CSC 0.18033688f   // 0.125 * log2(e)

static __device__ __forceinline__ unsigned short f2bf(float f) {
    union { float f; unsigned u; } x; x.f = f;
    unsigned r = x.u + 0x7fffu + ((x.u >> 16) & 1u);
    return (unsigned short)(r >> 16);
}
static __device__ __forceinline__ float bf2f(unsigned short h) {
    union { unsigned u; float f; } x; x.u = ((unsigned)h) << 16;
    return x.f;
}
static __device__ __forceinline__ float fexp2(float x) {
    return __builtin_amdgcn_exp2f(fminf(x, 60.f));
}

// ---- K staging: 16 floats/thread (row tid>>2, cols (tid&3)*16 ..+15)
static __device__ __forceinline__ void loadT(f32x4 (&t)[4], const float* __restrict__ src, int tid) {
    const int r = tid >> 2, d0 = (tid & 3) * 16;
    const float* s = src + r * 64 + d0;
    t[0] = *(const f32x4*)(s + 0);
    t[1] = *(const f32x4*)(s + 4);
    t[2] = *(const f32x4*)(s + 8);
    t[3] = *(const f32x4*)(s + 12);
}
// row-major bf16 store, XOR-swizzled (validated layout)
static __device__ __forceinline__ void writeK(unsigned short* dst, const f32x4 (&t)[4], int tid) {
    const int r = tid >> 2, d0 = (tid & 3) * 16;
    #pragma unroll
    for (int h = 0; h < 2; ++h) {
        short8 pk;
        #pragma unroll
        for (int i = 0; i < 8; ++i) {
            const int e = h * 8 + i;
            pk[i] = (short)f2bf(t[e >> 2][e & 3]);
        }
        *(short8*)&dst[((r * 64 + d0 + h * 8) ^ ((r & 7) << 3))] = pk;
    }
}
// ---- V staging: 4x4 block transpose. load: rows s0..s0+3, cols d0..d0+3
static __device__ __forceinline__ void loadV(f32x4 (&t)[4], const float* __restrict__ src, int tid) {
    const int s0 = (tid >> 4) * 4, d0 = (tid & 15) * 4;
    #pragma unroll
    for (int i = 0; i < 4; ++i)
        t[i] = *(const f32x4*)(src + (s0 + i) * 64 + d0);
}
// write transposed: Vt[dd][s0..s0+3] via ds_write_b64, same swizzle as read side
static __device__ __forceinline__ void writeVT(unsigned short* dst, const f32x4 (&t)[4], int tid) {
    const int s0 = (tid >> 4) * 4, d0 = (tid & 15) * 4;
    #pragma unroll
    for (int j = 0; j < 4; ++j) {
        const int dd = d0 + j;
        u16x4 pk;
        #pragma unroll
        for (int i = 0; i < 4; ++i) pk[i] = f2bf(t[i][j]);
        *(u16x4*)&dst[((dd * 64 + s0) ^ ((dd & 7) << 3))] = pk;
    }
}

__global__ __launch_bounds__(256, 3) void relattn(
    const float* __restrict__ qg, const float* __restrict__ kg,
    const float* __restrict__ vg, const float* __restrict__ embk,
    const float* __restrict__ embv,
    float* __restrict__ outg, float* __restrict__ attng)
{
    // 53376 B total -> 3 blocks/CU (160 KiB / 3 = 54613)
    __shared__ __align__(16) unsigned char lds[53376];
    unsigned short* QPt   = (unsigned short*)(lds);           //  8192: Q -> P
    // K buffers at 8192 + (buf<<13); V buffers at 24576 + (buf<<13)
    float*          biasS = (float*)(lds + 40960);            //  8448: fp32 [64][33]
    unsigned short* wS    = (unsigned short*)(lds + 49408);   //  3968: bf16 [64][31]
    float*          embvS = (float*)(lds);                    //  epilogue alias

    const int tid  = threadIdx.x;
    const int lane = tid & 63;
    const int wv   = tid >> 6;
    const int g16  = lane >> 4;
    const int l16  = lane & 15;
    const int rbase = wv * 16 + g16 * 4;

    // XCD swizzle: all 16 t-tiles of a bh group on one XCD (L2-resident K/V)
    const int lg = ((blockIdx.x & 7) << 7) | (blockIdx.x >> 3);
    const int bh = lg >> 4;
    const int t0 = (lg & 15) * 64;
    const int dtile = t0 >> 6;
    const long base = (long)bh * (T_ * D_);

    // ---------- prologue ----------
    {
        f32x4 qt[4];
        loadT(qt, qg + base + (long)t0 * D_, tid);
        writeK(QPt, qt, tid);
    }
    for (int i = tid; i < 64 * 31; i += 256) wS[i] = 0;
    __syncthreads();

    // bias[r][j] = CSC * (q_fp32[t0+r] . emb_k[j])
    for (int p = tid; p < 64 * 33; p += 256) {
        const int r = p / 33, j = p - r * 33;
        const float* qr = qg + base + (long)(t0 + r) * D_;
        const float* er = embk + j * D_;
        float acc = 0.f;
        #pragma unroll
        for (int d = 0; d < 64; d += 4) {
            f32x4 a = *(const f32x4*)(qr + d);
            f32x4 b = *(const f32x4*)(er + d);
            acc += a[0] * b[0] + a[1] * b[1] + a[2] * b[2] + a[3] * b[3];
        }
        biasS[r * 33 + j] = acc * CSC;
    }

    // hoist Q A-frags (rows 16*wv + l16)
    short8 qfrag[2];
    {
        const int r = wv * 16 + l16;
        const int sw = (r & 7) << 3;
        qfrag[0] = *(short8*)&QPt[((r * 64 + 0  + g16 * 8) ^ sw)];
        qfrag[1] = *(short8*)&QPt[((r * 64 + 32 + g16 * 8) ^ sw)];
    }

    f32x4 kreg[4];
    loadT(kreg, kg + base, tid);             // K tile 0 in flight
    __syncthreads();                         // biasS visible; tile 0 landed

    float bias_m[4], bias_p[4];
    #pragma unroll
    for (int j = 0; j < 4; ++j) {
        bias_m[j] = biasS[(rbase + j) * 33 + 0];
        bias_p[j] = biasS[(rbase + j) * 33 + 32];
    }

    {   // stage K tile 0, prefetch tile 1
        writeK((unsigned short*)(lds + 8192), kreg, tid);
        loadT(kreg, kg + base + (long)64 * D_, tid);
        __syncthreads();                     // Kb0 visible; tile 1 landed
    }

    // ---------- sweep 1: Z only, double-buffered single-barrier ----------
    float zacc[4] = {0.f, 0.f, 0.f, 0.f};
    for (int tile = 0; tile < 16; ++tile) {
        unsigned short* Kc = (unsigned short*)(lds + 8192 + ((tile & 1) << 13));
        if (tile < 15) {
            unsigned short* Kn = (unsigned short*)(lds + 8192 + (((tile + 1) & 1) << 13));
            writeK(Kn, kreg, tid);           // tile+1 from landed regs
            if (tile < 14) loadT(kreg, kg + base + (long)(tile + 2) * 64 * D_, tid);
        }
        f32x4 acc[4];
        #pragma unroll
        for (int sc = 0; sc < 4; ++sc) {
            f32x4 a = {0.f, 0.f, 0.f, 0.f};
            #pragma unroll
            for (int ks = 0; ks < 2; ++ks) {
                const int r = sc * 16 + l16;
                short8 bf = *(short8*)&Kc[((r * 64 + ks * 32 + g16 * 8) ^ ((r & 7) << 3))];
                a = __builtin_amdgcn_mfma_f32_16x16x32_bf16(qfrag[ks], bf, a, 0, 0, 0);
            }
            acc[sc] = a;
        }
        if (tile < dtile - 1) {
            #pragma unroll
            for (int j = 0; j < 4; ++j)
                #pragma unroll
                for (int sc = 0; sc < 4; ++sc)
                    zacc[j] += fexp2(fmaf(acc[sc][j], CSC, bias_m[j]));
        } else if (tile > dtile + 1) {
            #pragma unroll
            for (int j = 0; j < 4; ++j)
                #pragma unroll
                for (int sc = 0; sc < 4; ++sc)
                    zacc[j] += fexp2(fmaf(acc[sc][j], CSC, bias_p[j]));
        } else {
            #pragma unroll
            for (int j = 0; j < 4; ++j) {
                const int rl = rbase + j;
                const int tg = t0 + rl;
                #pragma unroll
                for (int sc = 0; sc < 4; ++sc) {
                    const int sg = tile * 64 + sc * 16 + l16;
                    int dsr = sg - tg;
                    int dc = dsr < -16 ? -16 : (dsr > 16 ? 16 : dsr);
                    const float b = biasS[rl * 33 + dc + 16];
                    zacc[j] += fexp2(fmaf(acc[sc][j], CSC, b));
                }
            }
        }
        __syncthreads();   // next K buf visible; prefetch landed (overlapped compute)
    }
    float iZ[4];
    #pragma unroll
    for (int j = 0; j < 4; ++j) {
        float z = zacc[j];
        #pragma unroll
        for (int o = 1; o < 16; o <<= 1) z += __shfl_xor(z, o);
        iZ[j] = 1.f / z;
    }

    // ---------- sweep 2 prologue: stage tile 0, prefetch tile 1 ----------
    f32x4 vreg[4];
    loadT(kreg, kg + base, tid);
    loadV(vreg, vg + base, tid);
    writeK ((unsigned short*)(lds + 8192),  kreg, tid);
    writeVT((unsigned short*)(lds + 24576), vreg, tid);
    loadT(kreg, kg + base + (long)64 * D_, tid);
    loadV(vreg, vg + base + (long)64 * D_, tid);
    __syncthreads();   // bufs 0 visible; tile 1 landed

    // ---------- sweep 2: attn write + PV ----------
    f32x4 oacc[4];
    {
        f32x4 z = {0.f, 0.f, 0.f, 0.f};
        #pragma unroll
        for (int dc = 0; dc < 4; ++dc) oacc[dc] = z;
    }
    float ps0[4]  = {0.f, 0.f, 0.f, 0.f};
    float ps32[4] = {0.f, 0.f, 0.f, 0.f};
    float* attnB = attng + (long)bh * T_ * T_;

    for (int tile = 0; tile < 16; ++tile) {
        unsigned short* Kc = (unsigned short*)(lds + 8192  + ((tile & 1) << 13));
        unsigned short* Vc = (unsigned short*)(lds + 24576 + ((tile & 1) << 13));
        if (tile < 15) {
            unsigned short* Kn = (unsigned short*)(lds + 8192  + (((tile + 1) & 1) << 13));
            unsigned short* Vn = (unsigned short*)(lds + 24576 + (((tile + 1) & 1) << 13));
            writeK (Kn, kreg, tid);
            writeVT(Vn, vreg, tid);
            if (tile < 14) {
                loadT(kreg, kg + base + (long)(tile + 2) * 64 * D_, tid);
                loadV(vreg, vg + base + (long)(tile + 2) * 64 * D_, tid);
            }
        }

        f32x4 acc[4];
        #pragma unroll
        for (int sc = 0; sc < 4; ++sc) {
            f32x4 a = {0.f, 0.f, 0.f, 0.f};
            #pragma unroll
            for (int ks = 0; ks < 2; ++ks) {
                const int r = sc * 16 + l16;
                short8 bf = *(short8*)&Kc[((r * 64 + ks * 32 + g16 * 8) ^ ((r & 7) << 3))];
                a = __builtin_amdgcn_mfma_f32_16x16x32_bf16(qfrag[ks], bf, a, 0, 0, 0);
            }
            acc[sc] = a;
        }

        if (tile < dtile - 1) {
            #pragma unroll
            for (int j = 0; j < 4; ++j) {
                const int rl = rbase + j;
                const int tg = t0 + rl;
                #pragma unroll
                for (int sc = 0; sc < 4; ++sc) {
                    const int sl = sc * 16 + l16;
                    const float a = fexp2(fmaf(acc[sc][j], CSC, bias_m[j])) * iZ[j];
                    attnB[(long)tg * T_ + tile * 64 + sl] = a;
                    QPt[((rl * 64 + sl) ^ ((rl & 7) << 3))] = f2bf(a);
                    ps0[j] += a;
                }
            }
        } else if (tile > dtile + 1) {
            #pragma unroll
            for (int j = 0; j < 4; ++j) {
                const int rl = rbase + j;
                const int tg = t0 + rl;
                #pragma unroll
                for (int sc = 0; sc < 4; ++sc) {
                    const int sl = sc * 16 + l16;
                    const float a = fexp2(fmaf(acc[sc][j], CSC, bias_p[j])) * iZ[j];
                    attnB[(long)tg * T_ + tile * 64 + sl] = a;
                    QPt[((rl * 64 + sl) ^ ((rl & 7) << 3))] = f2bf(a);
                    ps32[j] += a;
                }
            }
        } else {
            #pragma unroll
            for (int j = 0; j < 4; ++j) {
                const int rl = rbase + j;
                const int tg = t0 + rl;
                #pragma unroll
                for (int sc = 0; sc < 4; ++sc) {
                    const int sl = sc * 16 + l16;
                    const int sg = tile * 64 + sl;
                    const int dsr = sg - tg;
                    int dc = dsr < -16 ? -16 : (dsr > 16 ? 16 : dsr);
                    const float b = biasS[rl * 33 + dc + 16];
                    const float a = fexp2(fmaf(acc[sc][j], CSC, b)) * iZ[j];
                    attnB[(long)tg * T_ + sg] = a;
                    QPt[((rl * 64 + sl) ^ ((rl & 7) << 3))] = f2bf(a);
                    if (dsr <= -16)      ps0[j]  += a;
                    else if (dsr >= 16)  ps32[j] += a;
                    else                 wS[rl * 31 + dsr + 15] = f2bf(a);
                }
            }
        }

        // PV: A = P (own wave rows, same-wave LDS dep), B = V^T
        #pragma unroll
        for (int ks = 0; ks < 2; ++ks) {
            const int rp = wv * 16 + l16;
            short8 pa = *(short8*)&QPt[((rp * 64 + ks * 32 + g16 * 8) ^ ((rp & 7) << 3))];
            #pragma unroll
            for (int dc = 0; dc < 4; ++dc) {
                const int rv = dc * 16 + l16;
                short8 vb = *(short8*)&Vc[((rv * 64 + ks * 32 + g16 * 8) ^ ((rv & 7) << 3))];
                oacc[dc] = __builtin_amdgcn_mfma_f32_16x16x32_bf16(pa, vb, oacc[dc], 0, 0, 0);
            }
        }
        __syncthreads();   // next bufs visible; prefetch landed (overlapped)
    }

    // ---------- epilogue staging: emb_v into dead QPt/Kb0 region ----------
    for (int i = tid; i < 33 * 64; i += 256) embvS[i] = embv[i];

    // boundary-bucket reduction (register shuffles, overlaps staging)
    float w0r[4], w32r[4];
    #pragma unroll
    for (int j = 0; j < 4; ++j) {
        float a0 = ps0[j], a2 = ps32[j];
        #pragma unroll
        for (int o = 1; o < 16; o <<= 1) {
            a0 += __shfl_xor(a0, o);
            a2 += __shfl_xor(a2, o);
        }
        w0r[j] = a0; w32r[j] = a2;
    }
    __syncthreads();   // embvS + wS visible

    // ---------- epilogue: out = PV + sum_j w[t][j]*emb_v[j] ----------
    float vals[4][4];
    #pragma unroll
    for (int j = 0; j < 4; ++j)
        #pragma unroll
        for (int dc = 0; dc < 4; ++dc)
            vals[j][dc] = oacc[dc][j]
                        + w0r[j]  * embvS[0 * 64  + dc * 16 + l16]
                        + w32r[j] * embvS[32 * 64 + dc * 16 + l16];
    for (int jj = 1; jj < 32; ++jj) {
        float e[4];
        #pragma unroll
        for (int dc = 0; dc < 4; ++dc) e[dc] = embvS[jj * 64 + dc * 16 + l16];
        #pragma unroll
        for (int j = 0; j < 4; ++j) {
            const float w = bf2f(wS[(rbase + j) * 31 + jj - 1]);
            #pragma unroll
            for (int dc = 0; dc < 4; ++dc) vals[j][dc] += w * e[dc];
        }
    }
    #pragma unroll
    for (int j = 0; j < 4; ++j) {
        const int tg = t0 + rbase + j;
        #pragma unroll
        for (int dc = 0; dc < 4; ++dc)
            outg[base + (long)tg * D_ + dc * 16 + l16] = vals[j][dc];
    }
}

extern "C" void kernel_launch(void* const* d_in, const int* in_sizes, int n_in,
                              void* d_out, int out_size, void* d_ws, size_t ws_size,
                              hipStream_t stream) {
    const float* q    = (const float*)d_in[0];
    const float* k    = (const float*)d_in[1];
    const float* v    = (const float*)d_in[2];
    const float* embk = (const float*)d_in[3];
    const float* embv = (const float*)d_in[4];
    float* out  = (float*)d_out;
    float* attn = out + (long)4 * 16 * 1024 * 64;
    relattn<<<dim3(4 * 16 * 16), dim3(256), 0, stream>>>(q, k, v, embk, embv, out, attn);
}